// Round 1
// baseline (1735.941 us; speedup 1.0000x reference)
//
#include <hip/hip_runtime.h>

#define DIM_ 768
#define H_ 6
#define HD_ 128
#define NB_ 4
#define SEQ_ 2048
#define TOK_ (NB_*SEQ_)
#define OUT3_ (3*DIM_)

#define BM 64
#define BN 64
#define BK 16

// ---------------- mask kernel ----------------
__global__ void mask_kernel(const float* __restrict__ latency,
                            const float* __restrict__ rw,
                            const float* __restrict__ rb,
                            const float* __restrict__ g1,
                            const float* __restrict__ g2,
                            float* __restrict__ mask6) {
  int i = threadIdx.x;
  if (i < 6) {
    int j = (i < 4) ? 0 : (i - 3);
    float logit = rw[j] * latency[0] + rb[j];
    float z = (logit + g1[j] - g2[j]) / 5.0f;
    float ys = 1.0f / (1.0f + expf(-z));
    float yh = ys > 0.5f ? 1.0f : 0.0f;
    mask6[i] = (yh - ys) + ys;   // == forward value of straight-through mask
  }
}

// ---------------- QKV GEMM: qkv = x @ qkv_w^T + b, scatter to q/k/v [b,h,n,d] ----------------
__global__ __launch_bounds__(256)
void qkv_gemm_kernel(const float* __restrict__ A,   // (8192, 768) row-major
                     const float* __restrict__ W,   // (2304, 768) row-major
                     const float* __restrict__ bias,
                     float* __restrict__ qbuf, float* __restrict__ kbuf,
                     float* __restrict__ vbuf) {
  __shared__ float As[BK][BM + 4];   // k-major, stride 68 (16B aligned)
  __shared__ float Bs[BK][BN + 4];
  const int tx = threadIdx.x, ty = threadIdx.y;
  const int tid = ty * 16 + tx;
  const int t0 = blockIdx.y * BM;
  const int o0 = blockIdx.x * BN;
  const int lr = tid >> 2;
  const int lc4 = (tid & 3) << 2;
  float acc[4][4] = {};

  for (int k0 = 0; k0 < DIM_; k0 += BK) {
    __syncthreads();
    float4 av = *reinterpret_cast<const float4*>(A + (size_t)(t0 + lr) * DIM_ + k0 + lc4);
    float4 bv = *reinterpret_cast<const float4*>(W + (size_t)(o0 + lr) * DIM_ + k0 + lc4);
    As[lc4 + 0][lr] = av.x; As[lc4 + 1][lr] = av.y; As[lc4 + 2][lr] = av.z; As[lc4 + 3][lr] = av.w;
    Bs[lc4 + 0][lr] = bv.x; Bs[lc4 + 1][lr] = bv.y; Bs[lc4 + 2][lr] = bv.z; Bs[lc4 + 3][lr] = bv.w;
    __syncthreads();
#pragma unroll
    for (int kk = 0; kk < BK; ++kk) {
      float4 a4 = *reinterpret_cast<const float4*>(&As[kk][ty * 4]);
      float4 b4 = *reinterpret_cast<const float4*>(&Bs[kk][tx * 4]);
      float aa[4] = {a4.x, a4.y, a4.z, a4.w};
      float bb[4] = {b4.x, b4.y, b4.z, b4.w};
#pragma unroll
      for (int i = 0; i < 4; ++i)
#pragma unroll
        for (int j = 0; j < 4; ++j)
          acc[i][j] += aa[i] * bb[j];
    }
  }

  const float scale = 0.08838834764831845f;  // 128^-0.5
#pragma unroll
  for (int i = 0; i < 4; ++i) {
    int t = t0 + ty * 4 + i;
    int b = t / SEQ_, n = t % SEQ_;
#pragma unroll
    for (int j = 0; j < 4; ++j) {
      int o = o0 + tx * 4 + j;
      float val = acc[i][j] + bias[o];
      int s = o / DIM_;
      int rem = o - s * DIM_;
      int h = rem >> 7;
      int d = rem & 127;
      float* dst = (s == 0) ? qbuf : (s == 1) ? kbuf : vbuf;
      if (s == 0) val *= scale;
      dst[((size_t)(b * H_ + h) * SEQ_ + n) * HD_ + d] = val;
    }
  }
}

// ---------------- proj GEMM: out = abuf @ proj_w^T + b ----------------
__global__ __launch_bounds__(256)
void proj_gemm_kernel(const float* __restrict__ A,   // (8192, 768) row-major
                      const float* __restrict__ W,   // (768, 768) row-major
                      const float* __restrict__ bias,
                      float* __restrict__ out) {
  __shared__ float As[BK][BM + 4];
  __shared__ float Bs[BK][BN + 4];
  const int tx = threadIdx.x, ty = threadIdx.y;
  const int tid = ty * 16 + tx;
  const int t0 = blockIdx.y * BM;
  const int o0 = blockIdx.x * BN;
  const int lr = tid >> 2;
  const int lc4 = (tid & 3) << 2;
  float acc[4][4] = {};

  for (int k0 = 0; k0 < DIM_; k0 += BK) {
    __syncthreads();
    float4 av = *reinterpret_cast<const float4*>(A + (size_t)(t0 + lr) * DIM_ + k0 + lc4);
    float4 bv = *reinterpret_cast<const float4*>(W + (size_t)(o0 + lr) * DIM_ + k0 + lc4);
    As[lc4 + 0][lr] = av.x; As[lc4 + 1][lr] = av.y; As[lc4 + 2][lr] = av.z; As[lc4 + 3][lr] = av.w;
    Bs[lc4 + 0][lr] = bv.x; Bs[lc4 + 1][lr] = bv.y; Bs[lc4 + 2][lr] = bv.z; Bs[lc4 + 3][lr] = bv.w;
    __syncthreads();
#pragma unroll
    for (int kk = 0; kk < BK; ++kk) {
      float4 a4 = *reinterpret_cast<const float4*>(&As[kk][ty * 4]);
      float4 b4 = *reinterpret_cast<const float4*>(&Bs[kk][tx * 4]);
      float aa[4] = {a4.x, a4.y, a4.z, a4.w};
      float bb[4] = {b4.x, b4.y, b4.z, b4.w};
#pragma unroll
      for (int i = 0; i < 4; ++i)
#pragma unroll
        for (int j = 0; j < 4; ++j)
          acc[i][j] += aa[i] * bb[j];
    }
  }

#pragma unroll
  for (int i = 0; i < 4; ++i) {
    int t = t0 + ty * 4 + i;
    int o = o0 + tx * 4;
    float4 r;
    r.x = acc[i][0] + bias[o + 0];
    r.y = acc[i][1] + bias[o + 1];
    r.z = acc[i][2] + bias[o + 2];
    r.w = acc[i][3] + bias[o + 3];
    *reinterpret_cast<float4*>(out + (size_t)t * DIM_ + o) = r;
  }
}

// ---------------- flash attention (fp32), 64-row Q tile, 32-key tiles ----------------
__global__ __launch_bounds__(256)
void attn_kernel(const float* __restrict__ qbuf, const float* __restrict__ kbuf,
                 const float* __restrict__ vbuf, const float* __restrict__ mask6,
                 float* __restrict__ attnout) {
  __shared__ float Qs[64][132];
  __shared__ float Ks[32][132];
  __shared__ float Vs[32][128];
  __shared__ float Ss[64][33];
  __shared__ float mrow[64], lrow[64], crow[64];

  const int tid = threadIdx.x;
  const int bid = blockIdx.x;
  const int qt = bid & 31;          // 32 q-tiles
  const int bh = bid >> 5;          // 0..23
  const int h = bh % H_;
  const int b = bh / H_;
  const int q0 = qt * 64;
  const size_t base = (size_t)bh * SEQ_ * HD_;

  // load Q tile (pre-scaled q)
  {
    int r = tid >> 2;
    int c0 = (tid & 3) * 32;
    const float* src = qbuf + base + (size_t)(q0 + r) * HD_ + c0;
#pragma unroll
    for (int u = 0; u < 8; ++u)
      *reinterpret_cast<float4*>(&Qs[r][c0 + u * 4]) =
          *reinterpret_cast<const float4*>(src + u * 4);
  }
  if (tid < 64) { mrow[tid] = -3.0e38f; lrow[tid] = 0.0f; }

  float4 acc[2][4] = {};            // rows r2, r2+32 ; d = db*16 + u*4
  const int r2 = tid & 31;
  const int db = tid >> 5;          // 0..7
  const int cg = tid & 7;           // phase4: cols cg*4..cg*4+3
  const int rg = tid >> 3;          // phase4: rows rg*2, rg*2+1

  for (int j0 = 0; j0 < SEQ_; j0 += 32) {
    __syncthreads();
    {
      int r = tid >> 3;
      int c0 = (tid & 7) * 16;
      const float* ksrc = kbuf + base + (size_t)(j0 + r) * HD_ + c0;
      const float* vsrc = vbuf + base + (size_t)(j0 + r) * HD_ + c0;
#pragma unroll
      for (int u = 0; u < 4; ++u) {
        *reinterpret_cast<float4*>(&Ks[r][c0 + u * 4]) =
            *reinterpret_cast<const float4*>(ksrc + u * 4);
        *reinterpret_cast<float4*>(&Vs[r][c0 + u * 4]) =
            *reinterpret_cast<const float4*>(vsrc + u * 4);
      }
    }
    __syncthreads();
    // S = Q·K^T  (q already scaled)
    {
      float s[2][4] = {};
#pragma unroll 4
      for (int d4 = 0; d4 < 32; ++d4) {
        float4 qa = *reinterpret_cast<const float4*>(&Qs[rg * 2 + 0][d4 * 4]);
        float4 qb = *reinterpret_cast<const float4*>(&Qs[rg * 2 + 1][d4 * 4]);
#pragma unroll
        for (int jj = 0; jj < 4; ++jj) {
          float4 kv = *reinterpret_cast<const float4*>(&Ks[cg * 4 + jj][d4 * 4]);
          s[0][jj] += qa.x * kv.x + qa.y * kv.y + qa.z * kv.z + qa.w * kv.w;
          s[1][jj] += qb.x * kv.x + qb.y * kv.y + qb.z * kv.z + qb.w * kv.w;
        }
      }
#pragma unroll
      for (int ii = 0; ii < 2; ++ii)
#pragma unroll
        for (int jj = 0; jj < 4; ++jj)
          Ss[rg * 2 + ii][cg * 4 + jj] = s[ii][jj];
    }
    __syncthreads();
    // online softmax row update
    if (tid < 64) {
      int r = tid;
      float tmax = Ss[r][0];
#pragma unroll
      for (int j = 1; j < 32; ++j) tmax = fmaxf(tmax, Ss[r][j]);
      float mo = mrow[r];
      float nm = fmaxf(mo, tmax);
      float corr = expf(mo - nm);
      float sum = 0.f;
#pragma unroll
      for (int j = 0; j < 32; ++j) {
        float p = expf(Ss[r][j] - nm);
        Ss[r][j] = p;
        sum += p;
      }
      lrow[r] = lrow[r] * corr + sum;
      mrow[r] = nm;
      crow[r] = corr;
    }
    __syncthreads();
    // rescale + PV
    {
      float c0 = crow[r2];
      float c1 = crow[r2 + 32];
#pragma unroll
      for (int u = 0; u < 4; ++u) {
        acc[0][u].x *= c0; acc[0][u].y *= c0; acc[0][u].z *= c0; acc[0][u].w *= c0;
        acc[1][u].x *= c1; acc[1][u].y *= c1; acc[1][u].z *= c1; acc[1][u].w *= c1;
      }
#pragma unroll 4
      for (int j = 0; j < 32; ++j) {
        float p0 = Ss[r2][j];
        float p1 = Ss[r2 + 32][j];
#pragma unroll
        for (int u = 0; u < 4; ++u) {
          float4 v = *reinterpret_cast<const float4*>(&Vs[j][db * 16 + u * 4]);
          acc[0][u].x += p0 * v.x; acc[0][u].y += p0 * v.y;
          acc[0][u].z += p0 * v.z; acc[0][u].w += p0 * v.w;
          acc[1][u].x += p1 * v.x; acc[1][u].y += p1 * v.y;
          acc[1][u].z += p1 * v.z; acc[1][u].w += p1 * v.w;
        }
      }
    }
  }

  // epilogue: divide by l, apply head mask, write [t, c] layout
  float hm = mask6[h];
  float inv0 = hm / lrow[r2];
  float inv1 = hm / lrow[r2 + 32];
#pragma unroll
  for (int u = 0; u < 4; ++u) {
    int n0 = q0 + r2;
    int n1 = q0 + r2 + 32;
    float4 o0v = acc[0][u];
    o0v.x *= inv0; o0v.y *= inv0; o0v.z *= inv0; o0v.w *= inv0;
    float4 o1v = acc[1][u];
    o1v.x *= inv1; o1v.y *= inv1; o1v.z *= inv1; o1v.w *= inv1;
    size_t c = (size_t)h * HD_ + db * 16 + u * 4;
    *reinterpret_cast<float4*>(attnout + (size_t)(b * SEQ_ + n0) * DIM_ + c) = o0v;
    *reinterpret_cast<float4*>(attnout + (size_t)(b * SEQ_ + n1) * DIM_ + c) = o1v;
  }
}

extern "C" void kernel_launch(void* const* d_in, const int* in_sizes, int n_in,
                              void* d_out, int out_size, void* d_ws, size_t ws_size,
                              hipStream_t stream) {
  const float* x        = (const float*)d_in[0];
  const float* latency  = (const float*)d_in[1];
  const float* qkv_w    = (const float*)d_in[2];
  const float* qkv_b    = (const float*)d_in[3];
  const float* proj_w   = (const float*)d_in[4];
  const float* proj_b   = (const float*)d_in[5];
  const float* router_w = (const float*)d_in[6];
  const float* router_b = (const float*)d_in[7];
  const float* g1       = (const float*)d_in[8];
  const float* g2       = (const float*)d_in[9];
  float* out = (float*)d_out;

  const size_t per = (size_t)NB_ * H_ * SEQ_ * HD_;   // 6291456 floats
  const size_t need_bytes = (64 + 4 * per) * sizeof(float);
  if (ws_size < need_bytes) return;  // workspace too small — fail loudly via wrong output

  float* ws    = (float*)d_ws;
  float* mask6 = ws;
  float* qbuf  = ws + 64;
  float* kbuf  = qbuf + per;
  float* vbuf  = kbuf + per;
  float* abuf  = vbuf + per;

  mask_kernel<<<1, 64, 0, stream>>>(latency, router_w, router_b, g1, g2, mask6);
  qkv_gemm_kernel<<<dim3(OUT3_ / BN, TOK_ / BM), dim3(16, 16), 0, stream>>>(
      x, qkv_w, qkv_b, qbuf, kbuf, vbuf);
  attn_kernel<<<dim3(NB_ * H_ * (SEQ_ / 64)), dim3(256), 0, stream>>>(
      qbuf, kbuf, vbuf, mask6, abuf);
  proj_gemm_kernel<<<dim3(DIM_ / BN, TOK_ / BM), dim3(16, 16), 0, stream>>>(
      abuf, proj_w, proj_b, out);
}

// Round 2
// 323.899 us; speedup vs baseline: 5.3595x; 5.3595x over previous
//
#include <hip/hip_runtime.h>
#include <cstdint>

#define DIM_ 768
#define H_ 6
#define HD_ 128
#define NB_ 4
#define SEQ_ 2048
#define TOK_ (NB_*SEQ_)
#define OUT3_ (3*DIM_)
#define L2E 1.4426950408889634f

typedef __bf16 bf16;
typedef __bf16 bf16x4 __attribute__((ext_vector_type(4)));
typedef __bf16 bf16x8 __attribute__((ext_vector_type(8)));
typedef float f32x4 __attribute__((ext_vector_type(4)));

__device__ __forceinline__ void gload16(const void* g, void* lds) {
  __builtin_amdgcn_global_load_lds((const __attribute__((address_space(1))) void*)g,
                                   (__attribute__((address_space(3))) void*)lds,
                                   16, 0, 0);
}

// ---------------- fp32 -> bf16 convert ----------------
__global__ void convert_kernel(const float* __restrict__ in, bf16* __restrict__ out, int n) {
  int i = (blockIdx.x * 256 + threadIdx.x) * 4;
  if (i >= n) return;
  float4 v = *reinterpret_cast<const float4*>(in + i);
  bf16x4 o = { (bf16)v.x, (bf16)v.y, (bf16)v.z, (bf16)v.w };
  *reinterpret_cast<bf16x4*>(out + i) = o;
}

// ---------------- mask kernel ----------------
__global__ void mask_kernel(const float* __restrict__ latency,
                            const float* __restrict__ rw,
                            const float* __restrict__ rb,
                            const float* __restrict__ g1,
                            const float* __restrict__ g2,
                            float* __restrict__ mask6) {
  int i = threadIdx.x;
  if (i < 6) {
    int j = (i < 4) ? 0 : (i - 3);
    float logit = rw[j] * latency[0] + rb[j];
    float z = (logit + g1[j] - g2[j]) / 5.0f;
    float ys = 1.0f / (1.0f + expf(-z));
    float yh = ys > 0.5f ? 1.0f : 0.0f;
    mask6[i] = (yh - ys) + ys;
  }
}

// ---------------- QKV GEMM (bf16 MFMA): qkv = x @ qkv_w^T + b ----------------
// scatter: q (scaled) -> [bh][n][d], k -> [bh][n][d], v -> [bh][d][n] (transposed)
__global__ __launch_bounds__(256)
void qkv_gemm(const bf16* __restrict__ A, const bf16* __restrict__ W,
              const float* __restrict__ bias,
              bf16* __restrict__ q, bf16* __restrict__ k, bf16* __restrict__ vt) {
  __shared__ bf16 As[128 * 32];
  __shared__ bf16 Bs[128 * 32];
  const int tid = threadIdx.x;
  const int l = tid & 63, w = tid >> 6;
  const int lr = l & 15, lg = l >> 4;
  const int wm = w >> 1, wn = w & 1;
  const int tm = blockIdx.y * 128;
  const int on = blockIdx.x * 128;

  f32x4 acc[4][4];
#pragma unroll
  for (int i = 0; i < 4; ++i)
#pragma unroll
    for (int j = 0; j < 4; ++j) acc[i][j] = f32x4{0.f, 0.f, 0.f, 0.f};

  for (int k0 = 0; k0 < DIM_; k0 += 32) {
    __syncthreads();
#pragma unroll
    for (int u = 0; u < 2; ++u) {
      int row = w * 32 + u * 16 + (l >> 2);
      int cb = l & 3;
      gload16(A + (size_t)(tm + row) * DIM_ + k0 + cb * 8, As + (w * 32 + u * 16) * 32);
      gload16(W + (size_t)(on + row) * DIM_ + k0 + cb * 8, Bs + (w * 32 + u * 16) * 32);
    }
    __syncthreads();
    bf16x8 af[4], bfr[4];
#pragma unroll
    for (int i = 0; i < 4; ++i)
      af[i] = *reinterpret_cast<const bf16x8*>(As + (wm * 64 + i * 16 + lr) * 32 + lg * 8);
#pragma unroll
    for (int j = 0; j < 4; ++j)
      bfr[j] = *reinterpret_cast<const bf16x8*>(Bs + (wn * 64 + j * 16 + lr) * 32 + lg * 8);
#pragma unroll
    for (int i = 0; i < 4; ++i)
#pragma unroll
      for (int j = 0; j < 4; ++j)
        acc[i][j] = __builtin_amdgcn_mfma_f32_16x16x32_bf16(af[i], bfr[j], acc[i][j], 0, 0, 0);
  }

  const float scale = 0.08838834764831845f;  // 128^-0.5
#pragma unroll
  for (int i = 0; i < 4; ++i) {
    int t = tm + wm * 64 + i * 16 + lg * 4;
#pragma unroll
    for (int j = 0; j < 4; ++j) {
      int o = on + wn * 64 + j * 16 + lr;
      int s = o / DIM_;
      int rem = o - s * DIM_;
      int hh = rem >> 7, d = rem & 127;
      float bia = bias[o];
#pragma unroll
      for (int r = 0; r < 4; ++r) {
        int tt = t + r;
        int bb = tt >> 11, n = tt & 2047;
        float val = acc[i][j][r] + bia;
        if (s == 0)
          q[((size_t)(bb * H_ + hh) * SEQ_ + n) * HD_ + d] = (bf16)(val * scale);
        else if (s == 1)
          k[((size_t)(bb * H_ + hh) * SEQ_ + n) * HD_ + d] = (bf16)val;
        else
          vt[((size_t)(bb * H_ + hh) * HD_ + d) * SEQ_ + n] = (bf16)val;
      }
    }
  }
}

// ---------------- proj GEMM (bf16 MFMA): out = ab @ proj_w^T + b (fp32 out) ----------------
__global__ __launch_bounds__(256)
void proj_gemm(const bf16* __restrict__ A, const bf16* __restrict__ W,
               const float* __restrict__ bias, float* __restrict__ out) {
  __shared__ bf16 As[128 * 32];
  __shared__ bf16 Bs[128 * 32];
  const int tid = threadIdx.x;
  const int l = tid & 63, w = tid >> 6;
  const int lr = l & 15, lg = l >> 4;
  const int wm = w >> 1, wn = w & 1;
  const int tm = blockIdx.y * 128;
  const int on = blockIdx.x * 128;

  f32x4 acc[4][4];
#pragma unroll
  for (int i = 0; i < 4; ++i)
#pragma unroll
    for (int j = 0; j < 4; ++j) acc[i][j] = f32x4{0.f, 0.f, 0.f, 0.f};

  for (int k0 = 0; k0 < DIM_; k0 += 32) {
    __syncthreads();
#pragma unroll
    for (int u = 0; u < 2; ++u) {
      int row = w * 32 + u * 16 + (l >> 2);
      int cb = l & 3;
      gload16(A + (size_t)(tm + row) * DIM_ + k0 + cb * 8, As + (w * 32 + u * 16) * 32);
      gload16(W + (size_t)(on + row) * DIM_ + k0 + cb * 8, Bs + (w * 32 + u * 16) * 32);
    }
    __syncthreads();
    bf16x8 af[4], bfr[4];
#pragma unroll
    for (int i = 0; i < 4; ++i)
      af[i] = *reinterpret_cast<const bf16x8*>(As + (wm * 64 + i * 16 + lr) * 32 + lg * 8);
#pragma unroll
    for (int j = 0; j < 4; ++j)
      bfr[j] = *reinterpret_cast<const bf16x8*>(Bs + (wn * 64 + j * 16 + lr) * 32 + lg * 8);
#pragma unroll
    for (int i = 0; i < 4; ++i)
#pragma unroll
      for (int j = 0; j < 4; ++j)
        acc[i][j] = __builtin_amdgcn_mfma_f32_16x16x32_bf16(af[i], bfr[j], acc[i][j], 0, 0, 0);
  }

#pragma unroll
  for (int i = 0; i < 4; ++i) {
#pragma unroll
    for (int j = 0; j < 4; ++j) {
      int o = on + wn * 64 + j * 16 + lr;
      float bia = bias[o];
#pragma unroll
      for (int r = 0; r < 4; ++r) {
        int t = tm + wm * 64 + i * 16 + lg * 4 + r;
        out[(size_t)t * DIM_ + o] = acc[i][j][r] + bia;
      }
    }
  }
}

// ---------------- flash attention, bf16 MFMA ----------------
// block: 1 head-batch (bh), 128 q-rows, 4 waves (32 rows each); K/V tiles of 64
__global__ __launch_bounds__(256)
void attn_kernel(const bf16* __restrict__ qb, const bf16* __restrict__ kb,
                 const bf16* __restrict__ vtb, const float* __restrict__ mask6,
                 bf16* __restrict__ ab) {
  __shared__ bf16 Ks[64 * 128];    // swizzled: LDS[r][blk] = K[r][blk^(r&7)], 16B blocks
  __shared__ bf16 Vts[128 * 64];   // swizzled: LDS[d][blk] = Vt[d][blk^(d&7)]
  __shared__ bf16 Ps[4 * 32 * 64]; // per-wave P, swizzled

  const int tid = threadIdx.x;
  const int l = tid & 63;
  const int w = tid >> 6;
  const int lr = l & 15, lg = l >> 4;
  const int bid = blockIdx.x;
  const int bh = bid % 24;         // same head -> same XCD (24 ≡ 0 mod 8)
  const int qt = bid / 24;
  const int h = bh % H_;
  const int b = bh / H_;
  const int q0 = qt * 128;

  const bf16* qg = qb + (size_t)bh * SEQ_ * HD_;
  const bf16* kg = kb + (size_t)bh * SEQ_ * HD_;
  const bf16* vg = vtb + (size_t)bh * HD_ * SEQ_;

  // Q fragments held in registers for the whole kernel
  bf16x8 qf[2][4];
#pragma unroll
  for (int rf = 0; rf < 2; ++rf)
#pragma unroll
    for (int kc = 0; kc < 4; ++kc)
      qf[rf][kc] = *reinterpret_cast<const bf16x8*>(
          qg + (size_t)(q0 + w * 32 + rf * 16 + lr) * HD_ + kc * 32 + lg * 8);

  f32x4 oacc[2][8];
  float mrun[2][4], lrun[2][4];
#pragma unroll
  for (int rf = 0; rf < 2; ++rf) {
#pragma unroll
    for (int df = 0; df < 8; ++df) oacc[rf][df] = f32x4{0.f, 0.f, 0.f, 0.f};
#pragma unroll
    for (int r = 0; r < 4; ++r) { mrun[rf][r] = -3.0e38f; lrun[rf][r] = 0.f; }
  }

  bf16* Pw = Ps + w * 2048;

  for (int j0 = 0; j0 < SEQ_; j0 += 64) {
    __syncthreads();
    // stage K [64][128] and Vt [128][64], swizzled via pre-swizzled global source
#pragma unroll
    for (int u = 0; u < 4; ++u) {
      int rk = w * 16 + u * 4 + (l >> 4);
      int blkk = l & 15;
      gload16(kg + (size_t)(j0 + rk) * HD_ + ((blkk ^ (rk & 7)) << 3),
              Ks + (w * 16 + u * 4) * 128);
      int rv = w * 32 + u * 8 + (l >> 3);
      int blkv = l & 7;
      gload16(vg + (size_t)rv * SEQ_ + j0 + ((blkv ^ (rv & 7)) << 3),
              Vts + (w * 32 + u * 8) * 64);
    }
    __syncthreads();

    // S = Q K^T : rows = q-rows (wave's 32), cols = 64 keys
    f32x4 sacc[2][4];
#pragma unroll
    for (int rf = 0; rf < 2; ++rf)
#pragma unroll
      for (int cf = 0; cf < 4; ++cf) sacc[rf][cf] = f32x4{0.f, 0.f, 0.f, 0.f};
#pragma unroll
    for (int cf = 0; cf < 4; ++cf) {
      int n = cf * 16 + lr;
      bf16x8 bfr[4];
#pragma unroll
      for (int kc = 0; kc < 4; ++kc) {
        int byteoff = n * 256 + ((kc * 64 + lg * 16) ^ ((n & 7) << 4));
        bfr[kc] = *reinterpret_cast<const bf16x8*>((const char*)Ks + byteoff);
      }
#pragma unroll
      for (int rf = 0; rf < 2; ++rf)
#pragma unroll
        for (int kc = 0; kc < 4; ++kc)
          sacc[rf][cf] = __builtin_amdgcn_mfma_f32_16x16x32_bf16(qf[rf][kc], bfr[kc], sacc[rf][cf], 0, 0, 0);
    }

    // online softmax (rows live on fixed lg group; reduce across lr via shfl_xor)
    float corr[2][4];
#pragma unroll
    for (int rf = 0; rf < 2; ++rf)
#pragma unroll
      for (int r = 0; r < 4; ++r) {
        float t = fmaxf(fmaxf(sacc[rf][0][r], sacc[rf][1][r]),
                        fmaxf(sacc[rf][2][r], sacc[rf][3][r]));
        t = fmaxf(t, __shfl_xor(t, 1));
        t = fmaxf(t, __shfl_xor(t, 2));
        t = fmaxf(t, __shfl_xor(t, 4));
        t = fmaxf(t, __shfl_xor(t, 8));
        float nm = fmaxf(mrun[rf][r], t);
        float c = exp2f((mrun[rf][r] - nm) * L2E);
        corr[rf][r] = c;
        mrun[rf][r] = nm;
        float sum = 0.f;
#pragma unroll
        for (int cf = 0; cf < 4; ++cf) {
          float p = exp2f((sacc[rf][cf][r] - nm) * L2E);
          sacc[rf][cf][r] = p;
          sum += p;
        }
        sum += __shfl_xor(sum, 1);
        sum += __shfl_xor(sum, 2);
        sum += __shfl_xor(sum, 4);
        sum += __shfl_xor(sum, 8);
        lrun[rf][r] = lrun[rf][r] * c + sum;
      }

    // write P to per-wave LDS (bf16, swizzled)
#pragma unroll
    for (int rf = 0; rf < 2; ++rf)
#pragma unroll
      for (int r = 0; r < 4; ++r) {
        int m = rf * 16 + lg * 4 + r;
#pragma unroll
        for (int cf = 0; cf < 4; ++cf) {
          int kcol = cf * 16 + lr;
          int byteoff = (m * 128 + kcol * 2) ^ ((m & 7) << 4);
          *reinterpret_cast<bf16*>((char*)Pw + byteoff) = (bf16)sacc[rf][cf][r];
        }
      }

    // rescale O by corr
#pragma unroll
    for (int rf = 0; rf < 2; ++rf)
#pragma unroll
      for (int df = 0; df < 8; ++df)
#pragma unroll
        for (int r = 0; r < 4; ++r) oacc[rf][df][r] *= corr[rf][r];

    // PV: A = P (rows = q-rows, k = keys), B = V (k = keys, cols = d) from Vt
    bf16x8 pa[2][2];
#pragma unroll
    for (int rf = 0; rf < 2; ++rf)
#pragma unroll
      for (int kc = 0; kc < 2; ++kc) {
        int m = rf * 16 + lr;
        int byteoff = (m * 128 + (kc * 64 + lg * 16)) ^ ((m & 7) << 4);
        pa[rf][kc] = *reinterpret_cast<const bf16x8*>((const char*)Pw + byteoff);
      }
#pragma unroll
    for (int df = 0; df < 8; ++df) {
      int d = df * 16 + lr;
      bf16x8 vf[2];
#pragma unroll
      for (int kc = 0; kc < 2; ++kc) {
        int byteoff = (d * 128 + (kc * 64 + lg * 16)) ^ ((d & 7) << 4);
        vf[kc] = *reinterpret_cast<const bf16x8*>((const char*)Vts + byteoff);
      }
#pragma unroll
      for (int rf = 0; rf < 2; ++rf)
#pragma unroll
        for (int kc = 0; kc < 2; ++kc)
          oacc[rf][df] = __builtin_amdgcn_mfma_f32_16x16x32_bf16(pa[rf][kc], vf[kc], oacc[rf][df], 0, 0, 0);
    }
  }

  // epilogue: normalize, apply head mask, write bf16 [t][c]
  float hm = mask6[h];
#pragma unroll
  for (int rf = 0; rf < 2; ++rf) {
    float inv[4];
#pragma unroll
    for (int r = 0; r < 4; ++r) inv[r] = hm / lrun[rf][r];
#pragma unroll
    for (int df = 0; df < 8; ++df) {
      int c = h * HD_ + df * 16 + lr;
#pragma unroll
      for (int r = 0; r < 4; ++r) {
        int n = q0 + w * 32 + rf * 16 + lg * 4 + r;
        ab[((size_t)b * SEQ_ + n) * DIM_ + c] = (bf16)(oacc[rf][df][r] * inv[r]);
      }
    }
  }
}

extern "C" void kernel_launch(void* const* d_in, const int* in_sizes, int n_in,
                              void* d_out, int out_size, void* d_ws, size_t ws_size,
                              hipStream_t stream) {
  const float* x        = (const float*)d_in[0];
  const float* latency  = (const float*)d_in[1];
  const float* qkv_w    = (const float*)d_in[2];
  const float* qkv_b    = (const float*)d_in[3];
  const float* proj_w   = (const float*)d_in[4];
  const float* proj_b   = (const float*)d_in[5];
  const float* router_w = (const float*)d_in[6];
  const float* router_b = (const float*)d_in[7];
  const float* g1       = (const float*)d_in[8];
  const float* g2       = (const float*)d_in[9];
  float* out = (float*)d_out;

  const size_t N_X  = (size_t)TOK_ * DIM_;     // 6291456
  const size_t N_WQ = (size_t)OUT3_ * DIM_;    // 1769472
  const size_t N_WP = (size_t)DIM_ * DIM_;     // 589824
  const size_t N_P  = (size_t)NB_ * H_ * SEQ_ * HD_;  // 6291456

  float* maskp = (float*)d_ws;
  bf16* xb  = (bf16*)((char*)d_ws + 256);
  bf16* wqb = xb + N_X;
  bf16* wpb = wqb + N_WQ;
  bf16* qbf = wpb + N_WP;
  bf16* kbf = qbf + N_P;
  bf16* vtb = kbf + N_P;
  bf16* abf = vtb + N_P;

  size_t need = 256 + 2 * (N_X + N_WQ + N_WP + 4 * N_P);
  if (ws_size < need) return;

  convert_kernel<<<(int)(N_X / 1024), 256, 0, stream>>>(x, xb, (int)N_X);
  convert_kernel<<<(int)(N_WQ / 1024), 256, 0, stream>>>(qkv_w, wqb, (int)N_WQ);
  convert_kernel<<<(int)(N_WP / 1024), 256, 0, stream>>>(proj_w, wpb, (int)N_WP);
  mask_kernel<<<1, 64, 0, stream>>>(latency, router_w, router_b, g1, g2, maskp);

  qkv_gemm<<<dim3(OUT3_ / 128, TOK_ / 128), 256, 0, stream>>>(xb, wqb, qkv_b, qbf, kbf, vtb);
  attn_kernel<<<dim3(24 * (SEQ_ / 128)), 256, 0, stream>>>(qbf, kbf, vtb, maskp, abf);
  proj_gemm<<<dim3(DIM_ / 128, TOK_ / 128), 256, 0, stream>>>(abf, wpb, proj_b, out);
}

// Round 3
// 223.012 us; speedup vs baseline: 7.7841x; 1.4524x over previous
//
#include <hip/hip_runtime.h>
#include <cstdint>

#define DIM_ 768
#define H_ 6
#define HD_ 128
#define NB_ 4
#define SEQ_ 2048
#define TOK_ (NB_*SEQ_)
#define OUT3_ (3*DIM_)
#define L2E 1.4426950408889634f

typedef __bf16 bf16;
typedef __bf16 bf16x4 __attribute__((ext_vector_type(4)));
typedef __bf16 bf16x8 __attribute__((ext_vector_type(8)));
typedef float f32x4 __attribute__((ext_vector_type(4)));

__device__ __forceinline__ void gload16(const void* g, void* lds) {
  __builtin_amdgcn_global_load_lds((const __attribute__((address_space(1))) void*)g,
                                   (__attribute__((address_space(3))) void*)lds,
                                   16, 0, 0);
}

// ---------------- fp32 -> bf16 convert ----------------
__global__ void convert_kernel(const float* __restrict__ in, bf16* __restrict__ out, int n) {
  int i = (blockIdx.x * 256 + threadIdx.x) * 4;
  if (i >= n) return;
  float4 v = *reinterpret_cast<const float4*>(in + i);
  bf16x4 o = { (bf16)v.x, (bf16)v.y, (bf16)v.z, (bf16)v.w };
  *reinterpret_cast<bf16x4*>(out + i) = o;
}

// ---------------- mask kernel ----------------
__global__ void mask_kernel(const float* __restrict__ latency,
                            const float* __restrict__ rw,
                            const float* __restrict__ rb,
                            const float* __restrict__ g1,
                            const float* __restrict__ g2,
                            float* __restrict__ mask6) {
  int i = threadIdx.x;
  if (i < 6) {
    int j = (i < 4) ? 0 : (i - 3);
    float logit = rw[j] * latency[0] + rb[j];
    float z = (logit + g1[j] - g2[j]) / 5.0f;
    float ys = 1.0f / (1.0f + expf(-z));
    float yh = ys > 0.5f ? 1.0f : 0.0f;
    mask6[i] = (yh - ys) + ys;
  }
}

// ---------------- QKV GEMM (bf16 MFMA): qkv = x @ qkv_w^T + b ----------------
// scatter: q (scaled by 1/sqrt(d) * log2(e)) -> [bh][n][d], k -> [bh][n][d],
//          v -> [bh][d][n] (transposed)
__global__ __launch_bounds__(256)
void qkv_gemm(const bf16* __restrict__ A, const bf16* __restrict__ W,
              const float* __restrict__ bias,
              bf16* __restrict__ q, bf16* __restrict__ k, bf16* __restrict__ vt) {
  __shared__ bf16 As[128 * 32];
  __shared__ bf16 Bs[128 * 32];
  const int tid = threadIdx.x;
  const int l = tid & 63, w = tid >> 6;
  const int lr = l & 15, lg = l >> 4;
  const int wm = w >> 1, wn = w & 1;
  const int tm = blockIdx.y * 128;
  const int on = blockIdx.x * 128;

  f32x4 acc[4][4];
#pragma unroll
  for (int i = 0; i < 4; ++i)
#pragma unroll
    for (int j = 0; j < 4; ++j) acc[i][j] = f32x4{0.f, 0.f, 0.f, 0.f};

  for (int k0 = 0; k0 < DIM_; k0 += 32) {
    __syncthreads();
#pragma unroll
    for (int u = 0; u < 2; ++u) {
      int row = w * 32 + u * 16 + (l >> 2);
      int cb = l & 3;
      gload16(A + (size_t)(tm + row) * DIM_ + k0 + cb * 8, As + (w * 32 + u * 16) * 32);
      gload16(W + (size_t)(on + row) * DIM_ + k0 + cb * 8, Bs + (w * 32 + u * 16) * 32);
    }
    __syncthreads();
    bf16x8 af[4], bfr[4];
#pragma unroll
    for (int i = 0; i < 4; ++i)
      af[i] = *reinterpret_cast<const bf16x8*>(As + (wm * 64 + i * 16 + lr) * 32 + lg * 8);
#pragma unroll
    for (int j = 0; j < 4; ++j)
      bfr[j] = *reinterpret_cast<const bf16x8*>(Bs + (wn * 64 + j * 16 + lr) * 32 + lg * 8);
#pragma unroll
    for (int i = 0; i < 4; ++i)
#pragma unroll
      for (int j = 0; j < 4; ++j)
        acc[i][j] = __builtin_amdgcn_mfma_f32_16x16x32_bf16(af[i], bfr[j], acc[i][j], 0, 0, 0);
  }

  const float scale = 0.08838834764831845f * L2E;  // 128^-0.5 * log2(e)
#pragma unroll
  for (int i = 0; i < 4; ++i) {
    int t = tm + wm * 64 + i * 16 + lg * 4;
#pragma unroll
    for (int j = 0; j < 4; ++j) {
      int o = on + wn * 64 + j * 16 + lr;
      int s = o / DIM_;
      int rem = o - s * DIM_;
      int hh = rem >> 7, d = rem & 127;
      float bia = bias[o];
#pragma unroll
      for (int r = 0; r < 4; ++r) {
        int tt = t + r;
        int bb = tt >> 11, n = tt & 2047;
        float val = acc[i][j][r] + bia;
        if (s == 0)
          q[((size_t)(bb * H_ + hh) * SEQ_ + n) * HD_ + d] = (bf16)(val * scale);
        else if (s == 1)
          k[((size_t)(bb * H_ + hh) * SEQ_ + n) * HD_ + d] = (bf16)val;
        else
          vt[((size_t)(bb * H_ + hh) * HD_ + d) * SEQ_ + n] = (bf16)val;
      }
    }
  }
}

// ---------------- proj GEMM (bf16 MFMA): out = ab @ proj_w^T + b (fp32 out) ----------------
__global__ __launch_bounds__(256)
void proj_gemm(const bf16* __restrict__ A, const bf16* __restrict__ W,
               const float* __restrict__ bias, float* __restrict__ out) {
  __shared__ bf16 As[128 * 32];
  __shared__ bf16 Bs[128 * 32];
  const int tid = threadIdx.x;
  const int l = tid & 63, w = tid >> 6;
  const int lr = l & 15, lg = l >> 4;
  const int wm = w >> 1, wn = w & 1;
  const int tm = blockIdx.y * 128;
  const int on = blockIdx.x * 128;

  f32x4 acc[4][4];
#pragma unroll
  for (int i = 0; i < 4; ++i)
#pragma unroll
    for (int j = 0; j < 4; ++j) acc[i][j] = f32x4{0.f, 0.f, 0.f, 0.f};

  for (int k0 = 0; k0 < DIM_; k0 += 32) {
    __syncthreads();
#pragma unroll
    for (int u = 0; u < 2; ++u) {
      int row = w * 32 + u * 16 + (l >> 2);
      int cb = l & 3;
      gload16(A + (size_t)(tm + row) * DIM_ + k0 + cb * 8, As + (w * 32 + u * 16) * 32);
      gload16(W + (size_t)(on + row) * DIM_ + k0 + cb * 8, Bs + (w * 32 + u * 16) * 32);
    }
    __syncthreads();
    bf16x8 af[4], bfr[4];
#pragma unroll
    for (int i = 0; i < 4; ++i)
      af[i] = *reinterpret_cast<const bf16x8*>(As + (wm * 64 + i * 16 + lr) * 32 + lg * 8);
#pragma unroll
    for (int j = 0; j < 4; ++j)
      bfr[j] = *reinterpret_cast<const bf16x8*>(Bs + (wn * 64 + j * 16 + lr) * 32 + lg * 8);
#pragma unroll
    for (int i = 0; i < 4; ++i)
#pragma unroll
      for (int j = 0; j < 4; ++j)
        acc[i][j] = __builtin_amdgcn_mfma_f32_16x16x32_bf16(af[i], bfr[j], acc[i][j], 0, 0, 0);
  }

#pragma unroll
  for (int i = 0; i < 4; ++i) {
#pragma unroll
    for (int j = 0; j < 4; ++j) {
      int o = on + wn * 64 + j * 16 + lr;
      float bia = bias[o];
#pragma unroll
      for (int r = 0; r < 4; ++r) {
        int t = tm + wm * 64 + i * 16 + lg * 4 + r;
        out[(size_t)t * DIM_ + o] = acc[i][j][r] + bia;
      }
    }
  }
}

// ---------------- flash attention, bf16 MFMA ----------------
// QBLK=64 (4 waves x 16 q-rows), KVBLK=64, grid = 24 bh x 32 qtiles = 768 blocks
__global__ __launch_bounds__(256, 3)
void attn_kernel(const bf16* __restrict__ qb, const bf16* __restrict__ kb,
                 const bf16* __restrict__ vtb, const float* __restrict__ mask6,
                 bf16* __restrict__ ab) {
  __shared__ bf16 Ks[64 * 128];    // LDS[r][blk16] = K[r][blk16 ^ (r&7)]
  __shared__ bf16 Vts[128 * 64];   // LDS[d][blk16] = Vt[d][blk16 ^ (d&7)]
  __shared__ bf16 Ps[4 * 16 * 64]; // per-wave P [16 q-rows][64 keys], swizzled

  const int tid = threadIdx.x;
  const int l = tid & 63;
  const int w = tid >> 6;
  const int lr = l & 15, lg = l >> 4;
  const int bid = blockIdx.x;
  const int bh = bid % 24;         // XCD gets bids ≡ xcd (mod 8) -> 3 heads per XCD L2
  const int qt = bid / 24;
  const int h = bh % H_;
  const int b = bh / H_;
  const int q0 = qt * 64;

  const bf16* qg = qb + (size_t)bh * SEQ_ * HD_;
  const bf16* kg = kb + (size_t)bh * SEQ_ * HD_;
  const bf16* vg = vtb + (size_t)bh * HD_ * SEQ_;

  // Q fragments in registers for the whole kernel (wave's 16 rows)
  bf16x8 qf[4];
#pragma unroll
  for (int kc = 0; kc < 4; ++kc)
    qf[kc] = *reinterpret_cast<const bf16x8*>(
        qg + (size_t)(q0 + w * 16 + lr) * HD_ + kc * 32 + lg * 8);

  f32x4 oacc[8];
  float mrun[4], lrun[4];
#pragma unroll
  for (int df = 0; df < 8; ++df) oacc[df] = f32x4{0.f, 0.f, 0.f, 0.f};
#pragma unroll
  for (int r = 0; r < 4; ++r) { mrun[r] = -3.0e38f; lrun[r] = 0.f; }

  bf16* Pw = Ps + w * 1024;

  for (int j0 = 0; j0 < SEQ_; j0 += 64) {
    __syncthreads();
#pragma unroll
    for (int u = 0; u < 4; ++u) {
      int rk = w * 16 + u * 4 + (l >> 4);
      int blkk = l & 15;
      gload16(kg + (size_t)(j0 + rk) * HD_ + ((blkk ^ (rk & 7)) << 3),
              Ks + (w * 16 + u * 4) * 128);
      int rv = w * 32 + u * 8 + (l >> 3);
      int blkv = l & 7;
      gload16(vg + (size_t)rv * SEQ_ + j0 + ((blkv ^ (rv & 7)) << 3),
              Vts + (w * 32 + u * 8) * 64);
    }
    __syncthreads();

    // S = Q K^T : 16 q-rows x 64 keys (S already in log2 units via q scale)
    f32x4 sacc[4];
#pragma unroll
    for (int cf = 0; cf < 4; ++cf) sacc[cf] = f32x4{0.f, 0.f, 0.f, 0.f};
    __builtin_amdgcn_s_setprio(1);
#pragma unroll
    for (int cf = 0; cf < 4; ++cf) {
      int n = cf * 16 + lr;
#pragma unroll
      for (int kc = 0; kc < 4; ++kc) {
        int byteoff = n * 256 + ((kc * 64 + lg * 16) ^ ((n & 7) << 4));
        bf16x8 bfr = *reinterpret_cast<const bf16x8*>((const char*)Ks + byteoff);
        sacc[cf] = __builtin_amdgcn_mfma_f32_16x16x32_bf16(qf[kc], bfr, sacc[cf], 0, 0, 0);
      }
    }
    __builtin_amdgcn_s_setprio(0);

    // online softmax, defer-max (THR = 8 in log2 domain -> P bounded by 256)
    float tmax[4];
    bool need = false;
#pragma unroll
    for (int r = 0; r < 4; ++r) {
      float t = fmaxf(fmaxf(sacc[0][r], sacc[1][r]), fmaxf(sacc[2][r], sacc[3][r]));
      t = fmaxf(t, __shfl_xor(t, 1));
      t = fmaxf(t, __shfl_xor(t, 2));
      t = fmaxf(t, __shfl_xor(t, 4));
      t = fmaxf(t, __shfl_xor(t, 8));
      tmax[r] = t;
      need |= (t > mrun[r] + 8.0f);
    }
    if (__ballot(need) != 0ull) {
#pragma unroll
      for (int r = 0; r < 4; ++r) {
        float nm = fmaxf(mrun[r], tmax[r]);
        float c = exp2f(mrun[r] - nm);
        mrun[r] = nm;
        lrun[r] *= c;
#pragma unroll
        for (int df = 0; df < 8; ++df) oacc[df][r] *= c;
      }
    }
#pragma unroll
    for (int r = 0; r < 4; ++r) {
      int m = lg * 4 + r;
      float sum = 0.f;
#pragma unroll
      for (int cf = 0; cf < 4; ++cf) {
        float p = exp2f(sacc[cf][r] - mrun[r]);
        sum += p;
        int byteoff = (m * 128 + (cf * 16 + lr) * 2) ^ ((m & 7) << 4);
        *reinterpret_cast<bf16*>((char*)Pw + byteoff) = (bf16)p;
      }
      sum += __shfl_xor(sum, 1);
      sum += __shfl_xor(sum, 2);
      sum += __shfl_xor(sum, 4);
      sum += __shfl_xor(sum, 8);
      lrun[r] += sum;
    }

    // PV: A = P [q-rows x keys], B from Vt [d x keys]
    bf16x8 pa[2];
#pragma unroll
    for (int kc = 0; kc < 2; ++kc) {
      int byteoff = (lr * 128 + (kc * 64 + lg * 16)) ^ ((lr & 7) << 4);
      pa[kc] = *reinterpret_cast<const bf16x8*>((const char*)Pw + byteoff);
    }
    __builtin_amdgcn_s_setprio(1);
#pragma unroll
    for (int df = 0; df < 8; ++df) {
      int d = df * 16 + lr;
#pragma unroll
      for (int kc = 0; kc < 2; ++kc) {
        int byteoff = (d * 128 + (kc * 64 + lg * 16)) ^ ((d & 7) << 4);
        bf16x8 vf = *reinterpret_cast<const bf16x8*>((const char*)Vts + byteoff);
        oacc[df] = __builtin_amdgcn_mfma_f32_16x16x32_bf16(pa[kc], vf, oacc[df], 0, 0, 0);
      }
    }
    __builtin_amdgcn_s_setprio(0);
  }

  // epilogue: normalize, apply head mask, write bf16 [t][c]
  float hm = mask6[h];
  float inv[4];
#pragma unroll
  for (int r = 0; r < 4; ++r) inv[r] = hm / lrun[r];
#pragma unroll
  for (int df = 0; df < 8; ++df) {
    int c = h * HD_ + df * 16 + lr;
#pragma unroll
    for (int r = 0; r < 4; ++r) {
      int n = q0 + w * 16 + lg * 4 + r;
      ab[((size_t)b * SEQ_ + n) * DIM_ + c] = (bf16)(oacc[df][r] * inv[r]);
    }
  }
}

extern "C" void kernel_launch(void* const* d_in, const int* in_sizes, int n_in,
                              void* d_out, int out_size, void* d_ws, size_t ws_size,
                              hipStream_t stream) {
  const float* x        = (const float*)d_in[0];
  const float* latency  = (const float*)d_in[1];
  const float* qkv_w    = (const float*)d_in[2];
  const float* qkv_b    = (const float*)d_in[3];
  const float* proj_w   = (const float*)d_in[4];
  const float* proj_b   = (const float*)d_in[5];
  const float* router_w = (const float*)d_in[6];
  const float* router_b = (const float*)d_in[7];
  const float* g1       = (const float*)d_in[8];
  const float* g2       = (const float*)d_in[9];
  float* out = (float*)d_out;

  const size_t N_X  = (size_t)TOK_ * DIM_;
  const size_t N_WQ = (size_t)OUT3_ * DIM_;
  const size_t N_WP = (size_t)DIM_ * DIM_;
  const size_t N_P  = (size_t)NB_ * H_ * SEQ_ * HD_;

  float* maskp = (float*)d_ws;
  bf16* xb  = (bf16*)((char*)d_ws + 256);
  bf16* wqb = xb + N_X;
  bf16* wpb = wqb + N_WQ;
  bf16* qbf = wpb + N_WP;
  bf16* kbf = qbf + N_P;
  bf16* vtb = kbf + N_P;
  bf16* abf = vtb + N_P;

  size_t need = 256 + 2 * (N_X + N_WQ + N_WP + 4 * N_P);
  if (ws_size < need) return;

  convert_kernel<<<(int)(N_X / 1024), 256, 0, stream>>>(x, xb, (int)N_X);
  convert_kernel<<<(int)(N_WQ / 1024), 256, 0, stream>>>(qkv_w, wqb, (int)N_WQ);
  convert_kernel<<<(int)(N_WP / 1024), 256, 0, stream>>>(proj_w, wpb, (int)N_WP);
  mask_kernel<<<1, 64, 0, stream>>>(latency, router_w, router_b, g1, g2, maskp);

  qkv_gemm<<<dim3(OUT3_ / 128, TOK_ / 128), 256, 0, stream>>>(xb, wqb, qkv_b, qbf, kbf, vtb);
  attn_kernel<<<dim3(24 * (SEQ_ / 64)), 256, 0, stream>>>(qbf, kbf, vtb, maskp, abf);
  proj_gemm<<<dim3(DIM_ / 128, TOK_ / 128), 256, 0, stream>>>(abf, wpb, proj_b, out);
}

// Round 4
// 196.438 us; speedup vs baseline: 8.8371x; 1.1353x over previous
//
#include <hip/hip_runtime.h>
#include <cstdint>

#define DIM_ 768
#define H_ 6
#define HD_ 128
#define NB_ 4
#define SEQ_ 2048
#define TOK_ (NB_*SEQ_)
#define OUT3_ (3*DIM_)
#define L2E 1.4426950408889634f

typedef __bf16 bf16;
typedef __bf16 bf16x4 __attribute__((ext_vector_type(4)));
typedef __bf16 bf16x8 __attribute__((ext_vector_type(8)));
typedef float f32x4 __attribute__((ext_vector_type(4)));

__device__ __forceinline__ void gload16(const void* g, void* lds) {
  __builtin_amdgcn_global_load_lds((const __attribute__((address_space(1))) void*)g,
                                   (__attribute__((address_space(3))) void*)lds,
                                   16, 0, 0);
}

// ---------------- fp32 -> bf16 convert ----------------
__global__ void convert_kernel(const float* __restrict__ in, bf16* __restrict__ out, int n) {
  int i = (blockIdx.x * 256 + threadIdx.x) * 4;
  if (i >= n) return;
  float4 v = *reinterpret_cast<const float4*>(in + i);
  bf16x4 o = { (bf16)v.x, (bf16)v.y, (bf16)v.z, (bf16)v.w };
  *reinterpret_cast<bf16x4*>(out + i) = o;
}

// ---------------- mask kernel ----------------
__global__ void mask_kernel(const float* __restrict__ latency,
                            const float* __restrict__ rw,
                            const float* __restrict__ rb,
                            const float* __restrict__ g1,
                            const float* __restrict__ g2,
                            float* __restrict__ mask6) {
  int i = threadIdx.x;
  if (i < 6) {
    int j = (i < 4) ? 0 : (i - 3);
    float logit = rw[j] * latency[0] + rb[j];
    float z = (logit + g1[j] - g2[j]) / 5.0f;
    float ys = 1.0f / (1.0f + expf(-z));
    float yh = ys > 0.5f ? 1.0f : 0.0f;
    mask6[i] = (yh - ys) + ys;
  }
}

// ---------------- QKV GEMM (bf16 MFMA): qkv = x @ qkv_w^T + b ----------------
// q (scaled by 1/sqrt(d)*log2e) -> [bh][n][d], k -> [bh][n][d], v -> [bh][d][n]
__global__ __launch_bounds__(256)
void qkv_gemm(const bf16* __restrict__ A, const bf16* __restrict__ W,
              const float* __restrict__ bias,
              bf16* __restrict__ q, bf16* __restrict__ k, bf16* __restrict__ vt) {
  __shared__ bf16 As[128 * 32];
  __shared__ bf16 Bs[128 * 32];
  const int tid = threadIdx.x;
  const int l = tid & 63, w = tid >> 6;
  const int lr = l & 15, lg = l >> 4;
  const int wm = w >> 1, wn = w & 1;
  const int tm = blockIdx.y * 128;
  const int on = blockIdx.x * 128;

  f32x4 acc[4][4];
#pragma unroll
  for (int i = 0; i < 4; ++i)
#pragma unroll
    for (int j = 0; j < 4; ++j) acc[i][j] = f32x4{0.f, 0.f, 0.f, 0.f};

  for (int k0 = 0; k0 < DIM_; k0 += 32) {
    __syncthreads();
#pragma unroll
    for (int u = 0; u < 2; ++u) {
      int row = w * 32 + u * 16 + (l >> 2);
      int cb = l & 3;
      gload16(A + (size_t)(tm + row) * DIM_ + k0 + cb * 8, As + (w * 32 + u * 16) * 32);
      gload16(W + (size_t)(on + row) * DIM_ + k0 + cb * 8, Bs + (w * 32 + u * 16) * 32);
    }
    __syncthreads();
    bf16x8 af[4], bfr[4];
#pragma unroll
    for (int i = 0; i < 4; ++i)
      af[i] = *reinterpret_cast<const bf16x8*>(As + (wm * 64 + i * 16 + lr) * 32 + lg * 8);
#pragma unroll
    for (int j = 0; j < 4; ++j)
      bfr[j] = *reinterpret_cast<const bf16x8*>(Bs + (wn * 64 + j * 16 + lr) * 32 + lg * 8);
#pragma unroll
    for (int i = 0; i < 4; ++i)
#pragma unroll
      for (int j = 0; j < 4; ++j)
        acc[i][j] = __builtin_amdgcn_mfma_f32_16x16x32_bf16(af[i], bfr[j], acc[i][j], 0, 0, 0);
  }

  if (on < 2 * DIM_) {
    // q or k scatter (uniform per block)
    const int s = on / DIM_;
    const float scale = 0.08838834764831845f * L2E;
#pragma unroll
    for (int i = 0; i < 4; ++i) {
      int t = tm + wm * 64 + i * 16 + lg * 4;
#pragma unroll
      for (int j = 0; j < 4; ++j) {
        int o = on + wn * 64 + j * 16 + lr;
        int rem = o - s * DIM_;
        int hh = rem >> 7, d = rem & 127;
        float bia = bias[o];
#pragma unroll
        for (int r = 0; r < 4; ++r) {
          int tt = t + r;
          int bb = tt >> 11, n = tt & 2047;
          float val = acc[i][j][r] + bia;
          if (s == 0)
            q[((size_t)(bb * H_ + hh) * SEQ_ + n) * HD_ + d] = (bf16)(val * scale);
          else
            k[((size_t)(bb * H_ + hh) * SEQ_ + n) * HD_ + d] = (bf16)val;
        }
      }
    }
  } else {
    // v: transpose 128x128 tile through LDS, write [bh][d][n] coalesced
    const int hh = (on - 2 * DIM_) >> 7;
    const int bb = tm >> 11, n0 = tm & 2047;
    bf16(*Ts)[136] = reinterpret_cast<bf16(*)[136]>(As);  // 16 x 136 bf16
    for (int wc = 0; wc < 2; ++wc) {
#pragma unroll
      for (int j = 0; j < 4; ++j) {
        __syncthreads();
        if (wn == wc) {
          float bia = bias[on + wc * 64 + j * 16 + lr];
#pragma unroll
          for (int i = 0; i < 4; ++i) {
            bf16x4 pk;
#pragma unroll
            for (int r = 0; r < 4; ++r) pk[r] = (bf16)(acc[i][j][r] + bia);
            *reinterpret_cast<bf16x4*>(&Ts[lr][wm * 64 + i * 16 + lg * 4]) = pk;
          }
        }
        __syncthreads();
        int row = tid >> 4;
        int c8 = (tid & 15) * 8;
        bf16x8 v8 = *reinterpret_cast<const bf16x8*>(&Ts[row][c8]);
        int d = wc * 64 + j * 16 + row;
        *reinterpret_cast<bf16x8*>(
            vt + ((size_t)(bb * H_ + hh) * HD_ + d) * SEQ_ + n0 + c8) = v8;
      }
    }
  }
}

// ---------------- proj GEMM (bf16 MFMA): out = ab @ proj_w^T + b (fp32 out) ----------------
__global__ __launch_bounds__(256)
void proj_gemm(const bf16* __restrict__ A, const bf16* __restrict__ W,
               const float* __restrict__ bias, float* __restrict__ out) {
  __shared__ bf16 As[128 * 32];
  __shared__ bf16 Bs[128 * 32];
  const int tid = threadIdx.x;
  const int l = tid & 63, w = tid >> 6;
  const int lr = l & 15, lg = l >> 4;
  const int wm = w >> 1, wn = w & 1;
  const int tm = blockIdx.y * 128;
  const int on = blockIdx.x * 128;

  f32x4 acc[4][4];
#pragma unroll
  for (int i = 0; i < 4; ++i)
#pragma unroll
    for (int j = 0; j < 4; ++j) acc[i][j] = f32x4{0.f, 0.f, 0.f, 0.f};

  for (int k0 = 0; k0 < DIM_; k0 += 32) {
    __syncthreads();
#pragma unroll
    for (int u = 0; u < 2; ++u) {
      int row = w * 32 + u * 16 + (l >> 2);
      int cb = l & 3;
      gload16(A + (size_t)(tm + row) * DIM_ + k0 + cb * 8, As + (w * 32 + u * 16) * 32);
      gload16(W + (size_t)(on + row) * DIM_ + k0 + cb * 8, Bs + (w * 32 + u * 16) * 32);
    }
    __syncthreads();
    bf16x8 af[4], bfr[4];
#pragma unroll
    for (int i = 0; i < 4; ++i)
      af[i] = *reinterpret_cast<const bf16x8*>(As + (wm * 64 + i * 16 + lr) * 32 + lg * 8);
#pragma unroll
    for (int j = 0; j < 4; ++j)
      bfr[j] = *reinterpret_cast<const bf16x8*>(Bs + (wn * 64 + j * 16 + lr) * 32 + lg * 8);
#pragma unroll
    for (int i = 0; i < 4; ++i)
#pragma unroll
      for (int j = 0; j < 4; ++j)
        acc[i][j] = __builtin_amdgcn_mfma_f32_16x16x32_bf16(af[i], bfr[j], acc[i][j], 0, 0, 0);
  }

#pragma unroll
  for (int i = 0; i < 4; ++i) {
#pragma unroll
    for (int j = 0; j < 4; ++j) {
      int o = on + wn * 64 + j * 16 + lr;
      float bia = bias[o];
#pragma unroll
      for (int r = 0; r < 4; ++r) {
        int t = tm + wm * 64 + i * 16 + lg * 4 + r;
        out[(size_t)t * DIM_ + o] = acc[i][j][r] + bia;
      }
    }
  }
}

// ---------------- flash attention, bf16 MFMA, dbuf + 1 barrier/tile ----------------
// QBLK=64 (4 waves x 16 q-rows), KVBLK=64, grid = 24 bh x 32 qtiles = 768 blocks
__global__ __launch_bounds__(256, 2)
void attn_kernel(const bf16* __restrict__ qb, const bf16* __restrict__ kb,
                 const bf16* __restrict__ vtb, const float* __restrict__ mask6,
                 bf16* __restrict__ ab) {
  __shared__ bf16 Ks[2][64 * 128];    // LDS[r][blk16] = K[r][blk16 ^ (r&7)]
  __shared__ bf16 Vts[2][128 * 64];   // LDS[d][blk16] = Vt[d][blk16 ^ (d&7)]
  __shared__ bf16 Ps[4][16 * 64];     // per-wave P [16 q][64 k], 16B-block swizzled

  const int tid = threadIdx.x;
  const int l = tid & 63;
  const int w = tid >> 6;
  const int lr = l & 15, lg = l >> 4;
  const int bid = blockIdx.x;
  const int bh = bid % 24;            // all q-tiles of a head land on one XCD
  const int qt = bid / 24;
  const int h = bh % H_;
  const int b = bh / H_;
  const int q0 = qt * 64;

  const bf16* qg = qb + (size_t)bh * SEQ_ * HD_;
  const bf16* kg = kb + (size_t)bh * SEQ_ * HD_;
  const bf16* vg = vtb + (size_t)bh * HD_ * SEQ_;

  // Q fragments in registers (wave's 16 rows; lane lr = q-row, lg = k-slice)
  bf16x8 qf[4];
#pragma unroll
  for (int kc = 0; kc < 4; ++kc)
    qf[kc] = *reinterpret_cast<const bf16x8*>(
        qg + (size_t)(q0 + w * 16 + lr) * HD_ + kc * 32 + lg * 8);

  f32x4 oacc[8];
#pragma unroll
  for (int df = 0; df < 8; ++df) oacc[df] = f32x4{0.f, 0.f, 0.f, 0.f};
  float m_lane = -3.0e38f;            // running max for q-row = lr
  float m_rows[4], lrun[4];           // rows layout: q-row = lg*4 + r
#pragma unroll
  for (int r = 0; r < 4; ++r) { m_rows[r] = -3.0e38f; lrun[r] = 0.f; }

  bf16 one = (bf16)1.0f;
  bf16x8 ones8 = {one, one, one, one, one, one, one, one};
  char* Pw = (char*)&Ps[w][0];

  // staging: K rows via (l>>4), V rows via (l>>3); XOR pre-applied to global source
  auto STAGE = [&](int j0, int buf) {
#pragma unroll
    for (int u = 0; u < 4; ++u) {
      int rk = w * 16 + u * 4 + (l >> 4);
      int blkk = l & 15;
      gload16(kg + (size_t)(j0 + rk) * HD_ + ((blkk ^ (rk & 7)) << 3),
              &Ks[buf][(w * 16 + u * 4) * 128]);
      int rv = w * 32 + u * 8 + (l >> 3);
      int blkv = l & 7;
      gload16(vg + (size_t)rv * SEQ_ + j0 + ((blkv ^ (rv & 7)) << 3),
              &Vts[buf][(w * 32 + u * 8) * 64]);
    }
  };

  STAGE(0, 0);
  __syncthreads();                    // vmcnt(0) drain: tile 0 staged
  int cur = 0;

  for (int j0 = 0; j0 < SEQ_; j0 += 64) {
    int jn = (j0 + 64 < SEQ_) ? j0 + 64 : 0;
    STAGE(jn, cur ^ 1);               // prefetch next tile (hidden under compute)

    const char* Kc = (const char*)&Ks[cur][0];
    const char* Vc = (const char*)&Vts[cur][0];

    // S^T = K Q^T : lane holds S[key = cf*16 + lg*4 + r][q = lr]
    f32x4 sacc[4];
#pragma unroll
    for (int cf = 0; cf < 4; ++cf) sacc[cf] = f32x4{0.f, 0.f, 0.f, 0.f};
    __builtin_amdgcn_s_setprio(1);
#pragma unroll
    for (int cf = 0; cf < 4; ++cf) {
      int n = cf * 16 + lr;
#pragma unroll
      for (int kc = 0; kc < 4; ++kc) {
        int byteoff = n * 256 + ((kc * 64 + lg * 16) ^ ((n & 7) << 4));
        bf16x8 kf = *reinterpret_cast<const bf16x8*>(Kc + byteoff);
        sacc[cf] = __builtin_amdgcn_mfma_f32_16x16x32_bf16(kf, qf[kc], sacc[cf], 0, 0, 0);
      }
    }
    __builtin_amdgcn_s_setprio(0);

    // lane-local softmax for q-row = lr (S already in log2 units)
    float t = sacc[0][0];
#pragma unroll
    for (int cf = 0; cf < 4; ++cf)
#pragma unroll
      for (int r = 0; r < 4; ++r) t = fmaxf(t, sacc[cf][r]);
    t = fmaxf(t, __shfl_xor(t, 16));
    t = fmaxf(t, __shfl_xor(t, 32));
    bool need = t > m_lane + 8.0f;    // defer-max threshold (P bounded by 2^8)
    if (__ballot(need) != 0ull) {
      m_lane = fmaxf(m_lane, t);
#pragma unroll
      for (int r = 0; r < 4; ++r) {
        float tr = __shfl(t, lg * 4 + r);          // tmax of q-row lg*4+r
        float nmr = fmaxf(m_rows[r], tr);
        float c = exp2f(m_rows[r] - nmr);
        m_rows[r] = nmr;
        lrun[r] *= c;
#pragma unroll
        for (int df = 0; df < 8; ++df) oacc[df][r] *= c;
      }
    }

    // P = exp2(S - m), packed b64 writes: P[q=lr][key cf*16+lg*4 .. +3]
#pragma unroll
    for (int cf = 0; cf < 4; ++cf) {
      bf16x4 pk;
#pragma unroll
      for (int r = 0; r < 4; ++r) pk[r] = (bf16)exp2f(sacc[cf][r] - m_lane);
      int byteoff = lr * 128 + ((((cf << 1) + (lg >> 1)) ^ (lr & 7)) << 4) + ((lg & 1) << 3);
      *reinterpret_cast<bf16x4*>(Pw + byteoff) = pk;
    }

    // reload P as A-fragments (rows = q)
    bf16x8 pa[2];
#pragma unroll
    for (int kc = 0; kc < 2; ++kc) {
      int byteoff = lr * 128 + ((((kc << 2) + lg) ^ (lr & 7)) << 4);
      pa[kc] = *reinterpret_cast<const bf16x8*>(Pw + byteoff);
    }

    // row-sum via ones-MFMA: ssum[r] = sum_k P[q=lg*4+r][k]  (rows layout)
    f32x4 ssum = f32x4{0.f, 0.f, 0.f, 0.f};
    ssum = __builtin_amdgcn_mfma_f32_16x16x32_bf16(pa[0], ones8, ssum, 0, 0, 0);
    ssum = __builtin_amdgcn_mfma_f32_16x16x32_bf16(pa[1], ones8, ssum, 0, 0, 0);
#pragma unroll
    for (int r = 0; r < 4; ++r) lrun[r] += ssum[r];

    // PV: oacc[q=lg*4+r][d=df*16+lr]
    __builtin_amdgcn_s_setprio(1);
#pragma unroll
    for (int df = 0; df < 8; ++df) {
      int d = df * 16 + lr;
#pragma unroll
      for (int kc = 0; kc < 2; ++kc) {
        int byteoff = d * 128 + ((kc * 64 + lg * 16) ^ ((d & 7) << 4));
        bf16x8 vf = *reinterpret_cast<const bf16x8*>(Vc + byteoff);
        oacc[df] = __builtin_amdgcn_mfma_f32_16x16x32_bf16(pa[kc], vf, oacc[df], 0, 0, 0);
      }
    }
    __builtin_amdgcn_s_setprio(0);

    __syncthreads();                  // next tile staged + all reads of cur done
    cur ^= 1;
  }

  // epilogue: normalize, apply head mask, write bf16 [t][c]
  float hm = mask6[h];
  float inv[4];
#pragma unroll
  for (int r = 0; r < 4; ++r) inv[r] = hm / lrun[r];
#pragma unroll
  for (int df = 0; df < 8; ++df) {
    int c = h * HD_ + df * 16 + lr;
#pragma unroll
    for (int r = 0; r < 4; ++r) {
      int n = q0 + w * 16 + lg * 4 + r;
      ab[((size_t)b * SEQ_ + n) * DIM_ + c] = (bf16)(oacc[df][r] * inv[r]);
    }
  }
}

extern "C" void kernel_launch(void* const* d_in, const int* in_sizes, int n_in,
                              void* d_out, int out_size, void* d_ws, size_t ws_size,
                              hipStream_t stream) {
  const float* x        = (const float*)d_in[0];
  const float* latency  = (const float*)d_in[1];
  const float* qkv_w    = (const float*)d_in[2];
  const float* qkv_b    = (const float*)d_in[3];
  const float* proj_w   = (const float*)d_in[4];
  const float* proj_b   = (const float*)d_in[5];
  const float* router_w = (const float*)d_in[6];
  const float* router_b = (const float*)d_in[7];
  const float* g1       = (const float*)d_in[8];
  const float* g2       = (const float*)d_in[9];
  float* out = (float*)d_out;

  const size_t N_X  = (size_t)TOK_ * DIM_;
  const size_t N_WQ = (size_t)OUT3_ * DIM_;
  const size_t N_WP = (size_t)DIM_ * DIM_;
  const size_t N_P  = (size_t)NB_ * H_ * SEQ_ * HD_;

  float* maskp = (float*)d_ws;
  bf16* xb  = (bf16*)((char*)d_ws + 256);
  bf16* wqb = xb + N_X;
  bf16* wpb = wqb + N_WQ;
  bf16* qbf = wpb + N_WP;
  bf16* kbf = qbf + N_P;
  bf16* vtb = kbf + N_P;
  bf16* abf = vtb + N_P;

  size_t need = 256 + 2 * (N_X + N_WQ + N_WP + 4 * N_P);
  if (ws_size < need) return;

  convert_kernel<<<(int)(N_X / 1024), 256, 0, stream>>>(x, xb, (int)N_X);
  convert_kernel<<<(int)(N_WQ / 1024), 256, 0, stream>>>(qkv_w, wqb, (int)N_WQ);
  convert_kernel<<<(int)(N_WP / 1024), 256, 0, stream>>>(proj_w, wpb, (int)N_WP);
  mask_kernel<<<1, 64, 0, stream>>>(latency, router_w, router_b, g1, g2, maskp);

  qkv_gemm<<<dim3(OUT3_ / 128, TOK_ / 128), 256, 0, stream>>>(xb, wqb, qkv_b, qbf, kbf, vtb);
  attn_kernel<<<dim3(24 * (SEQ_ / 64)), 256, 0, stream>>>(qbf, kbf, vtb, maskp, abf);
  proj_gemm<<<dim3(DIM_ / 128, TOK_ / 128), 256, 0, stream>>>(abf, wpb, proj_b, out);
}